// Round 1
// 2595.404 us; speedup vs baseline: 1.1174x; 1.1174x over previous
//
#include <hip/hip_runtime.h>
#include <hip/hip_bf16.h>

// StructFormer forward, MI355X. Round 3: m97-structure GEMMs.
// - all weights + emb pre-converted to bf16 once per forward (bit-identical f2b)
// - gemm2: global_load_lds width-16 staging, [kq][row][8] LDS layout, 2 barriers/K-step
// - BM=128 for N>=1536 GEMMs, BM=64 for N=512 (keeps 256 blocks -> all CUs busy)
// - XCD-bijective swizzle on the 2528-block logits GEMM
// B=16 L=256 H=512 NH=8 DH=64 NL=6 NTOK=10000 P=4 K=9 DFF=2048

typedef unsigned short u16;
typedef unsigned char  u8;
typedef short short8 __attribute__((ext_vector_type(8)));
typedef float f32x4  __attribute__((ext_vector_type(4)));

static constexpr int CB=16, CL=256, CH=512, CNH=8, CDH=64, CNL=6;
static constexpr int CNTOK=10000, CP=4, CKS=9, CDFF=2048, CT=CB*CL;
static constexpr int NTOKP=10112;   // 10000 padded to multiple of 128

__device__ __forceinline__ u16 f2b(float x){
    union { float f; unsigned u; } v; v.f = x;
    unsigned r = v.u + 0x7fffu + ((v.u >> 16) & 1u);   // round-to-nearest-even
    return (u16)(r >> 16);
}
__device__ __forceinline__ float b2f(u16 u){
    union { unsigned u; float f; } v; v.u = ((unsigned)u) << 16; return v.f;
}
__device__ __forceinline__ unsigned pack2(float a, float b){
    return (unsigned)f2b(a) | ((unsigned)f2b(b) << 16);
}
__device__ __forceinline__ void gll16(const void* g, void* l){
    __builtin_amdgcn_global_load_lds(
        (__attribute__((address_space(1))) void*)g,
        (__attribute__((address_space(3))) void*)l, 16, 0, 0);
}

// ---------------------------------------------------------------- fp32 -> bf16 convert (pad tail with zeros)
__global__ __launch_bounds__(256) void cvt_k(const float* __restrict__ in,
    u16* __restrict__ out, long n, long total)
{
    long i = ((long)blockIdx.x * 256 + threadIdx.x) * 8;
    if (i >= total) return;
    uint4 o;
    if (i < n) {
        float4 a = *(const float4*)(in + i);
        float4 b = *(const float4*)(in + i + 4);
        o.x = pack2(a.x, a.y); o.y = pack2(a.z, a.w);
        o.z = pack2(b.x, b.y); o.w = pack2(b.z, b.w);
    } else { o.x = o.y = o.z = o.w = 0u; }
    *(uint4*)(out + i) = o;
}

// ---------------------------------------------------------------- embed (writes fp32 h + bf16 abuf + mask)
__global__ __launch_bounds__(256) void embed2_k(const int* __restrict__ x,
    const float* __restrict__ emb, float* __restrict__ h,
    u16* __restrict__ abuf, u8* __restrict__ maskb)
{
    int t = blockIdx.x, tid = threadIdx.x;
    int tok = x[t];
    if (tid == 0) maskb[t] = (tok != 0) ? 1 : 0;
    const float* e = emb + (size_t)tok * CH;
    float v0 = e[tid], v1 = e[tid + 256];
    float* hp = h + (size_t)t * CH;
    hp[tid] = v0; hp[tid + 256] = v1;
    u16* ap = abuf + (size_t)t * CH;
    ap[tid] = f2b(v0); ap[tid + 256] = f2b(v1);
}

// ---------------------------------------------------------------- layernorm
template<bool INBF, bool AFFINE, bool DOTANH>
__global__ __launch_bounds__(256) void ln_k(const void* __restrict__ in,
    const float* __restrict__ s, const float* __restrict__ b, u16* __restrict__ out)
{
    int t = blockIdx.x, tid = threadIdx.x;
    float x0, x1;
    if (INBF) {
        const u16* row = (const u16*)in + (size_t)t * CH;
        x0 = b2f(row[tid]); x1 = b2f(row[tid + 256]);
    } else {
        const float* row = (const float*)in + (size_t)t * CH;
        x0 = row[tid]; x1 = row[tid + 256];
    }
    float sum = x0 + x1, sq = x0*x0 + x1*x1;
    #pragma unroll
    for (int o = 32; o; o >>= 1) { sum += __shfl_down(sum, o); sq += __shfl_down(sq, o); }
    __shared__ float rs[4], rq[4];
    int w = tid >> 6, lane = tid & 63;
    if (lane == 0) { rs[w] = sum; rq[w] = sq; }
    __syncthreads();
    sum = rs[0] + rs[1] + rs[2] + rs[3];
    sq  = rq[0] + rq[1] + rq[2] + rq[3];
    float mean = sum * (1.f/512.f);
    float var  = fmaxf(sq * (1.f/512.f) - mean*mean, 0.f);
    float rstd = rsqrtf(var + 1e-5f);
    float y0 = (x0 - mean) * rstd, y1 = (x1 - mean) * rstd;
    if (AFFINE) {
        y0 = y0 * s[tid]       + b[tid];
        y1 = y1 * s[tid + 256] + b[tid + 256];
    }
    if (DOTANH) { y0 = tanhf(y0); y1 = tanhf(y1); }
    u16* o = out + (size_t)t * CH;
    o[tid] = f2b(y0); o[tid + 256] = f2b(y1);
}

// ---------------------------------------------------------------- conv weight transpose
// src fp32 [P][9][Cin][Cout] -> dst bf16 [P][Cout][9*Cin]
__global__ __launch_bounds__(256) void tp_conv(const float* __restrict__ src,
    u16* __restrict__ dst)
{
    __shared__ float tile[32][33];
    int z = blockIdx.z, p = z / 9, t = z % 9;
    int ci0 = blockIdx.y * 32, co0 = blockIdx.x * 32;
    int tx = threadIdx.x, ty = threadIdx.y;   // 32 x 8
    #pragma unroll
    for (int yy = 0; yy < 4; yy++) {
        int i = ty + yy*8;
        tile[i][tx] = src[((size_t)z*512 + ci0 + i)*512 + co0 + tx];
    }
    __syncthreads();
    #pragma unroll
    for (int yy = 0; yy < 4; yy++) {
        int i = ty + yy*8;
        dst[((size_t)p*512 + co0 + i)*4608 + (size_t)t*512 + ci0 + tx] = f2b(tile[tx][i]);
    }
}

// ---------------------------------------------------------------- MFMA GEMM, m97 structure
// C[M,N] = act(alpha * A @ B^T + bias); A bf16 [M][K] (or conv-gathered), B bf16 [Npad][K]
// (caller guarantees B rows padded to n0+128). OUT: 0 fp32, 1 bf16, 2 fp32 +=.
// Tile BM x 128 x 32; 256 threads = 4 waves (2x2); LDS layout [kq][row][8] bf16,
// staged linearly by global_load_lds (1KiB per wave chunk); frag reads are 2-way/bank (free).
template<int BM, bool CONV, int ACT, int OUT>
__global__ __launch_bounds__(256) void gemm2(
    const u16* __restrict__ A, const u16* __restrict__ B,
    const float* __restrict__ bias, void* __restrict__ Cv,
    const u8* __restrict__ mask,
    int M, int N, int K, float alpha, long sA, long sB, long sC, int swz)
{
    constexpr int MI = BM / 32;
    __shared__ __align__(16) u16 As[32 * BM];  // [4 kq][BM][8]
    __shared__ __align__(16) u16 Bs[4096];     // [4 kq][128][8]

    int bx = blockIdx.x, by = blockIdx.y;
    if (swz) {                                 // bijective: nwg % 8 == 0 guaranteed by caller
        int nwg = gridDim.x * gridDim.y;
        int bid = by * gridDim.x + bx;
        int s = (bid & 7) * (nwg >> 3) + (bid >> 3);
        bx = s % gridDim.x; by = s / gridDim.x;
    }
    const int tid  = threadIdx.x;
    const int lane = tid & 63, wave = tid >> 6;
    const int q = lane >> 4, ln = lane & 15;
    const int wm = wave >> 1, wn = wave & 1;
    const int m0 = by * BM, n0 = bx * 128;
    const int z  = blockIdx.z;
    A += (size_t)z * sA; B += (size_t)z * sB;

    f32x4 acc[MI][4];
    #pragma unroll
    for (int i = 0; i < MI; i++)
        #pragma unroll
        for (int j = 0; j < 4; j++)
            #pragma unroll
            for (int r = 0; r < 4; r++) acc[i][j][r] = 0.f;

    for (int k0 = 0; k0 < K; k0 += 32) {
        // ---- stage A ----
        if (!CONV) {
            if (BM == 128) {
                #pragma unroll
                for (int t = 0; t < 2; t++) {
                    int c = wave + t*4;                 // chunk 0..7: kq=c>>1, rows (c&1)*64+lane
                    int kq = c >> 1, rh = (c & 1) << 6;
                    gll16(A + (size_t)(m0 + rh + lane) * K + k0 + kq*8, As + c*512);
                }
            } else {
                // BM=64: chunk = wave = kq, rows = lane
                gll16(A + (size_t)(m0 + lane) * K + k0 + wave*8, As + wave*512);
            }
        } else {
            // conv gather (BM=64 only): thread = (kq=wave, row=lane); masked uint4 + ds_write
            int tap = k0 >> 9;                          // conv tap 0..8
            int ci  = (k0 & 511) + wave*8;
            int gr  = m0 + lane;
            int bb  = gr >> 8;
            int l2  = (gr & 255) + tap - 4;
            bool ok = ((unsigned)l2 < 256u) && mask[(bb << 8) | l2];
            uint4 v; v.x = v.y = v.z = v.w = 0u;
            if (ok) v = *(const uint4*)(A + ((size_t)((bb << 8) | l2)) * CH + ci);
            *(uint4*)&As[wave*512 + lane*8] = v;
        }
        // ---- stage B ----
        #pragma unroll
        for (int t = 0; t < 2; t++) {
            int c = wave + t*4;
            int kq = c >> 1, rh = (c & 1) << 6;
            gll16(B + (size_t)(n0 + rh + lane) * K + k0 + kq*8, Bs + c*512);
        }
        __syncthreads();
        short8 af[MI], bf[4];
        #pragma unroll
        for (int f = 0; f < MI; f++)
            af[f] = *(const short8*)&As[q*(BM*8) + (wm*(BM/2) + f*16 + ln)*8];
        #pragma unroll
        for (int g = 0; g < 4; g++)
            bf[g] = *(const short8*)&Bs[q*1024 + (wn*64 + g*16 + ln)*8];
        #pragma unroll
        for (int f = 0; f < MI; f++)
            #pragma unroll
            for (int g = 0; g < 4; g++)
                acc[f][g] = __builtin_amdgcn_mfma_f32_16x16x32_bf16(af[f], bf[g], acc[f][g], 0, 0, 0);
        __syncthreads();
    }
    // ---- epilogue ----
    float* Cf = (float*)Cv; u16* Cb = (u16*)Cv;
    #pragma unroll
    for (int f = 0; f < MI; f++) {
        int row0 = m0 + wm*(BM/2) + f*16 + q*4;
        #pragma unroll
        for (int g = 0; g < 4; g++) {
            int col = n0 + wn*64 + g*16 + ln;
            if (col < N) {
                #pragma unroll
                for (int r = 0; r < 4; r++) {
                    float v = acc[f][g][r] * alpha;
                    if (bias) v += bias[col];
                    if (ACT == 1) v = v > 0.f ? v : 0.01f * v;
                    size_t idx = (size_t)z * sC + (size_t)(row0 + r) * N + col;
                    if (OUT == 0)      Cf[idx] = v;
                    else if (OUT == 1) Cb[idx] = f2b(v);
                    else               Cf[idx] += v;
                }
            }
        }
    }
}

// ---------------------------------------------------------------- parser softmax
__global__ __launch_bounds__(256) void softmax_head(float* __restrict__ sc,
    const u8* __restrict__ mask)
{
    int bi = blockIdx.x;              // b*256 + i
    int b = bi >> 8, i = bi & 255;
    int j = threadIdx.x;
    float* rowp = sc + (size_t)bi * CL;
    bool valid = mask[(b << 8) | j] != 0;
    float v = valid ? rowp[j] : -1e30f;
    float mx = v;
    #pragma unroll
    for (int o = 32; o; o >>= 1) mx = fmaxf(mx, __shfl_down(mx, o));
    __shared__ float rm[4], rsum[4];
    int w = j >> 6, lane = j & 63;
    if (lane == 0) rm[w] = mx;
    __syncthreads();
    mx = fmaxf(fmaxf(rm[0], rm[1]), fmaxf(rm[2], rm[3]));
    float e = valid ? __expf(v - mx) : 0.f;
    float ssum = e;
    #pragma unroll
    for (int o = 32; o; o >>= 1) ssum += __shfl_down(ssum, o);
    if (lane == 0) rsum[w] = ssum;
    __syncthreads();
    ssum = rsum[0] + rsum[1] + rsum[2] + rsum[3];
    float r = e / fmaxf(ssum, 1e-30f);
    if (j == i) r = 0.f;
    rowp[j] = r;
}

// ---------------------------------------------------------------- attention
__global__ __launch_bounds__(256) void attn_k(const u16* __restrict__ qkv,
    const float* __restrict__ head, const float* __restrict__ relw,
    const u8* __restrict__ mask, u16* __restrict__ ctx, int layer)
{
    __shared__ __align__(16) u16 Ks[CL * CDH];
    __shared__ __align__(16) u16 Vs[CL * CDH];
    int bx = blockIdx.x;
    int b = bx >> 4, hd = (bx >> 1) & 7, qh = bx & 1;
    int tid = threadIdx.x;

    #pragma unroll
    for (int r = 0; r < 8; r++) {
        int ef = tid + 256 * r;
        int j = ef >> 3, d8 = (ef & 7) * 8;
        const u16* ps = qkv + (size_t)(b*256 + j) * 1536 + 512 + hd*64 + d8;
        *(uint4*)&Ks[j*64 + d8] = *(const uint4*)ps;
        *(uint4*)&Vs[j*64 + d8] = *(const uint4*)(ps + 512);
    }

    int qi = qh * 128 + (tid >> 1);
    int half = tid & 1;
    float qv[CDH];
    {
        const u16* qp = qkv + (size_t)(b*256 + qi) * 1536 + hd*64;
        #pragma unroll
        for (int c = 0; c < 8; c++) {
            uint4 u = *(const uint4*)(qp + c*8);
            unsigned uu[4] = {u.x, u.y, u.z, u.w};
            #pragma unroll
            for (int p2 = 0; p2 < 4; p2++) {
                qv[c*8 + p2*2]     = b2f((u16)(uu[p2] & 0xffffu));
                qv[c*8 + p2*2 + 1] = b2f((u16)(uu[p2] >> 16));
            }
        }
    }
    float r0 = relw[((layer << 3) + hd) * 2 + 0];
    float r1 = relw[((layer << 3) + hd) * 2 + 1];
    float e0 = __expf(r0), e1 = __expf(r1);
    float w0 = e0 / (e0 + e1), w1 = 1.f - w0;

    __syncthreads();

    const float* h1 = head + ((size_t)b << 16) + ((size_t)qi << 8);
    const float* h2 = head + ((size_t)b << 16) + qi;
    const u8* mb = mask + (b << 8);

    float m = -1e30f, lsum = 0.f;
    float acc[CDH];
    #pragma unroll
    for (int d = 0; d < CDH; d++) acc[d] = 0.f;

    for (int jj = 0; jj < 128; jj++) {
        int j = half * 128 + jj;
        if (!mb[j]) continue;
        float dot = 0.f;
        #pragma unroll
        for (int d = 0; d < CDH; d++) dot += qv[d] * b2f(Ks[(j << 6) + d]);
        float s = dot * 0.125f + w0 * h1[j] + w1 * h2[(size_t)j << 8];
        float mn = fmaxf(m, s);
        float c = __expf(m - mn);
        float p = __expf(s - mn);
        lsum = lsum * c + p;
        #pragma unroll
        for (int d = 0; d < CDH; d++) acc[d] = acc[d] * c + p * b2f(Vs[(j << 6) + d]);
        m = mn;
    }
    {
        float mo = __shfl_xor(m, 1);
        float lo = __shfl_xor(lsum, 1);
        float M  = fmaxf(m, mo);
        float cs = __expf(m - M);
        float co = __expf(mo - M);
        lsum = lsum * cs + lo * co;
        #pragma unroll
        for (int d = 0; d < CDH; d++) {
            float ao = __shfl_xor(acc[d], 1);
            acc[d] = acc[d] * cs + ao * co;
        }
    }
    if (half == 0) {
        float inv = 1.f / fmaxf(lsum, 1e-30f);
        u16* cp = ctx + (size_t)(b*256 + qi) * CH + (hd << 6);
        #pragma unroll
        for (int d = 0; d < CDH; d++) cp[d] = f2b(acc[d] * inv);
    }
}

// ---------------------------------------------------------------- launch
extern "C" void kernel_launch(void* const* d_in, const int* in_sizes, int n_in,
                              void* d_out, int out_size, void* d_ws, size_t ws_size,
                              hipStream_t stream)
{
    const int*   x        = (const int*)d_in[0];
    const float* emb      = (const float*)d_in[2];
    const float* conv_w   = (const float*)d_in[3];
    const float* conv_b   = (const float*)d_in[4];
    const float* parent_w = (const float*)d_in[5];
    const float* parent_b = (const float*)d_in[6];
    const float* child_w  = (const float*)d_in[7];
    const float* child_b  = (const float*)d_in[8];
    const float* rel_w    = (const float*)d_in[9];
    const float* qkv_w    = (const float*)d_in[10];
    const float* qkv_b    = (const float*)d_in[11];
    const float* out_w    = (const float*)d_in[12];
    const float* out_b    = (const float*)d_in[13];
    const float* ln1_s    = (const float*)d_in[14];
    const float* ln1_b    = (const float*)d_in[15];
    const float* ln2_s    = (const float*)d_in[16];
    const float* ln2_b    = (const float*)d_in[17];
    const float* ff1_w    = (const float*)d_in[18];
    const float* ff1_b    = (const float*)d_in[19];
    const float* ff2_w    = (const float*)d_in[20];
    const float* ff2_b    = (const float*)d_in[21];
    const float* norm_s   = (const float*)d_in[22];
    const float* norm_b   = (const float*)d_in[23];
    const float* out_bias = (const float*)d_in[24];

    float* ws = (float*)d_ws;
    // ---- workspace layout (float offsets) ----
    float* h      = ws;                                  // 0        fp32 residual (8 MB)
    float* headp  = ws + 2097152;                        // 4 MB fp32 (B,L,L)
    u16*   abuf   = (u16*)(ws + 3145728);                // 4 MB bf16 LN out
    u16*   Rb     = (u16*)(ws + 4194304);                // 12 MB region
    u16*   qkvb   = Rb;                                  //   qkv bf16 (12 MB)
    u16*   parentb= Rb;                                  //   parser alias
    u16*   childb = Rb + 2097152;
    u16*   convo  = Rb + 4194304;                        //   conv out bf16 (4 MB)
    u16*   ctxb   = (u16*)(ws + 7340032);                // 4 MB bf16 ctx
    u16*   ff1b   = (u16*)(ws + 8388608);                // 16 MB bf16 ff1
    u16*   convwb = (u16*)(ws + 7340032);                // conv W bf16 (18.9 MB, alias ctx+ff1; dead before transformer)
    u8*    maskb  = (u8*)(ws + 12582912);                // 4 KB
    u16*   ebf16  = (u16*)(ws + 12583936);               // emb bf16 padded [10112][512] (10.35 MB)
    u16*   qkvwb  = (u16*)(ws + 15172608);               // 9.4 MB
    u16*   outwb  = (u16*)(ws + 17531904);               // 3.1 MB
    u16*   ff1wb  = (u16*)(ws + 18318336);               // 12.6 MB
    u16*   ff2wb  = (u16*)(ws + 21464064);               // 12.6 MB
    u16*   parwb  = (u16*)(ws + 24609792);               // 0.5 MB
    u16*   chlwb  = (u16*)(ws + 24740864);               // 0.5 MB  (total ~99.5 MB)

    // ---- one-time weight conversion to bf16 (row-major [N][K] preserved) ----
    tp_conv<<<dim3(16,16,36), dim3(32,8), 0, stream>>>(conv_w, convwb);
    cvt_k<<<2528, 256, 0, stream>>>(emb,      ebf16, (long)CNTOK*CH, (long)NTOKP*CH);
    cvt_k<<<2304, 256, 0, stream>>>(qkv_w,    qkvwb, 4718592L, 4718592L);
    cvt_k<<< 768, 256, 0, stream>>>(out_w,    outwb, 1572864L, 1572864L);
    cvt_k<<<3072, 256, 0, stream>>>(ff1_w,    ff1wb, 6291456L, 6291456L);
    cvt_k<<<3072, 256, 0, stream>>>(ff2_w,    ff2wb, 6291456L, 6291456L);
    cvt_k<<< 128, 256, 0, stream>>>(parent_w, parwb,  262144L,  262144L);
    cvt_k<<< 128, 256, 0, stream>>>(child_w,  chlwb,  262144L,  262144L);

    // ---- embed (h fp32 + abuf bf16 + mask in one pass) ----
    embed2_k<<<CT, 256, 0, stream>>>(x, emb, h, abuf, maskb);

    // ---- parser ----
    for (int p = 0; p < CP; p++) {
        gemm2<64,true,0,1><<<dim3(4,64,1), 256, 0, stream>>>(
            abuf, convwb + (size_t)p*512*4608, conv_b + p*512, convo, maskb,
            CT, 512, 4608, 1.f, 0, 0, 0, 0);
        ln_k<true,false,true><<<CT, 256, 0, stream>>>(convo, nullptr, nullptr, abuf);
    }
    gemm2<64,false,0,1><<<dim3(4,64,1), 256, 0, stream>>>(
        abuf, parwb, parent_b, parentb, nullptr, CT, 512, 512, 1.f, 0, 0, 0, 0);
    gemm2<64,false,0,1><<<dim3(4,64,1), 256, 0, stream>>>(
        abuf, chlwb, child_b, childb, nullptr, CT, 512, 512, 1.f, 0, 0, 0, 0);
    gemm2<64,false,0,0><<<dim3(2,4,16), 256, 0, stream>>>(
        childb, parentb, nullptr, headp, nullptr, 256, 256, 512, 1.f/512.f,
        131072, 131072, 65536, 0);
    softmax_head<<<CT, 256, 0, stream>>>(headp, maskb);

    // ---- transformer ----
    for (int l = 0; l < CNL; l++) {
        ln_k<false,true,false><<<CT, 256, 0, stream>>>(h, ln1_s + l*CH, ln1_b + l*CH, abuf);
        gemm2<128,false,0,1><<<dim3(12,32,1), 256, 0, stream>>>(
            abuf, qkvwb + (size_t)l*1536*512, qkv_b + l*1536, qkvb, nullptr,
            CT, 1536, 512, 1.f, 0, 0, 0, 0);
        attn_k<<<256, 256, 0, stream>>>(qkvb, headp, rel_w, maskb, ctxb, l);
        gemm2<64,false,0,2><<<dim3(4,64,1), 256, 0, stream>>>(
            ctxb, outwb + (size_t)l*512*512, out_b + l*512, h, nullptr,
            CT, 512, 512, 1.f, 0, 0, 0, 0);
        ln_k<false,true,false><<<CT, 256, 0, stream>>>(h, ln2_s + l*CH, ln2_b + l*CH, abuf);
        gemm2<128,false,1,1><<<dim3(16,32,1), 256, 0, stream>>>(
            abuf, ff1wb + (size_t)l*2048*512, ff1_b + l*2048, ff1b, nullptr,
            CT, 2048, 512, 1.f, 0, 0, 0, 0);
        gemm2<64,false,0,2><<<dim3(4,64,1), 256, 0, stream>>>(
            ff1b, ff2wb + (size_t)l*512*2048, ff2_b + l*512, h, nullptr,
            CT, 512, 2048, 1.f, 0, 0, 0, 0);
    }
    ln_k<false,true,false><<<CT, 256, 0, stream>>>(h, norm_s, norm_b, abuf);
    // logits: 79x32 = 2528 blocks (div 8 -> bijective XCD swizzle on)
    gemm2<128,false,0,0><<<dim3(79,32,1), 256, 0, stream>>>(
        abuf, ebf16, out_bias, d_out, nullptr, CT, CNTOK, 512, 1.f, 0, 0, 0, 1);
}

// Round 2
// 2511.280 us; speedup vs baseline: 1.1549x; 1.0335x over previous
//
#include <hip/hip_runtime.h>
#include <hip/hip_bf16.h>

// StructFormer forward, MI355X. Round 4:
// - padded+premasked parser buffer [16][264][512] -> conv GEMM uses pure gll16 staging
// - split-K=2 + atomicAdd epilogue for the N=512 residual GEMMs (out-proj, ff2)
// - m-fast XCD-chunked block swizzle for logits/conv (B-panel L2 residency)
// - headT precomputed (into d_out scratch) -> coalesced bias reads in attention
// B=16 L=256 H=512 NH=8 DH=64 NL=6 NTOK=10000 P=4 K=9 DFF=2048

typedef unsigned short u16;
typedef unsigned char  u8;
typedef short short8 __attribute__((ext_vector_type(8)));
typedef float f32x4  __attribute__((ext_vector_type(4)));

static constexpr int CB=16, CL=256, CH=512, CNH=8, CDH=64, CNL=6;
static constexpr int CNTOK=10000, CP=4, CKS=9, CDFF=2048, CT=CB*CL;
static constexpr int NTOKP=10112;   // 10000 padded to multiple of 128
static constexpr int LP=264;        // padded parser row stride (4 halo + 256 + 4 halo)

__device__ __forceinline__ u16 f2b(float x){
    union { float f; unsigned u; } v; v.f = x;
    unsigned r = v.u + 0x7fffu + ((v.u >> 16) & 1u);   // round-to-nearest-even
    return (u16)(r >> 16);
}
__device__ __forceinline__ float b2f(u16 u){
    union { unsigned u; float f; } v; v.u = ((unsigned)u) << 16; return v.f;
}
__device__ __forceinline__ unsigned pack2(float a, float b){
    return (unsigned)f2b(a) | ((unsigned)f2b(b) << 16);
}
__device__ __forceinline__ void gll16(const void* g, void* l){
    __builtin_amdgcn_global_load_lds(
        (__attribute__((address_space(1))) void*)g,
        (__attribute__((address_space(3))) void*)l, 16, 0, 0);
}

// ---------------------------------------------------------------- fp32 -> bf16 convert (pad tail with zeros)
__global__ __launch_bounds__(256) void cvt_k(const float* __restrict__ in,
    u16* __restrict__ out, long n, long total)
{
    long i = ((long)blockIdx.x * 256 + threadIdx.x) * 8;
    if (i >= total) return;
    uint4 o;
    if (i < n) {
        float4 a = *(const float4*)(in + i);
        float4 b = *(const float4*)(in + i + 4);
        o.x = pack2(a.x, a.y); o.y = pack2(a.z, a.w);
        o.z = pack2(b.x, b.y); o.w = pack2(b.z, b.w);
    } else { o.x = o.y = o.z = o.w = 0u; }
    *(uint4*)(out + i) = o;
}

// ---------------------------------------------------------------- embed (fp32 h + masked padded bf16 + mask)
__global__ __launch_bounds__(256) void embed2_k(const int* __restrict__ x,
    const float* __restrict__ emb, float* __restrict__ h,
    u16* __restrict__ ppad, u8* __restrict__ maskb)
{
    int t = blockIdx.x, tid = threadIdx.x;
    int tok = x[t];
    bool mk = (tok != 0);
    if (tid == 0) maskb[t] = mk ? 1 : 0;
    const float* e = emb + (size_t)tok * CH;
    float v0 = e[tid], v1 = e[tid + 256];
    float* hp = h + (size_t)t * CH;
    hp[tid] = v0; hp[tid + 256] = v1;
    int pr = (t >> 8) * LP + 4 + (t & 255);
    u16* ap = ppad + (size_t)pr * CH;
    ap[tid]       = mk ? f2b(v0) : (u16)0;
    ap[tid + 256] = mk ? f2b(v1) : (u16)0;
}

// ---------------------------------------------------------------- layernorm
// OUTMODE 0: plain [4096][512] bf16; 1: padded parser layout + mask-zeroing
template<bool INBF, bool AFFINE, bool DOTANH, int OUTMODE>
__global__ __launch_bounds__(256) void ln_k(const void* __restrict__ in,
    const float* __restrict__ s, const float* __restrict__ b, u16* __restrict__ out,
    const u8* __restrict__ mask)
{
    int t = blockIdx.x, tid = threadIdx.x;
    float x0, x1;
    if (INBF) {
        const u16* row = (const u16*)in + (size_t)t * CH;
        x0 = b2f(row[tid]); x1 = b2f(row[tid + 256]);
    } else {
        const float* row = (const float*)in + (size_t)t * CH;
        x0 = row[tid]; x1 = row[tid + 256];
    }
    float sum = x0 + x1, sq = x0*x0 + x1*x1;
    #pragma unroll
    for (int o = 32; o; o >>= 1) { sum += __shfl_down(sum, o); sq += __shfl_down(sq, o); }
    __shared__ float rs[4], rq[4];
    int w = tid >> 6, lane = tid & 63;
    if (lane == 0) { rs[w] = sum; rq[w] = sq; }
    __syncthreads();
    sum = rs[0] + rs[1] + rs[2] + rs[3];
    sq  = rq[0] + rq[1] + rq[2] + rq[3];
    float mean = sum * (1.f/512.f);
    float var  = fmaxf(sq * (1.f/512.f) - mean*mean, 0.f);
    float rstd = rsqrtf(var + 1e-5f);
    float y0 = (x0 - mean) * rstd, y1 = (x1 - mean) * rstd;
    if (AFFINE) {
        y0 = y0 * s[tid]       + b[tid];
        y1 = y1 * s[tid + 256] + b[tid + 256];
    }
    if (DOTANH) { y0 = tanhf(y0); y1 = tanhf(y1); }
    if (OUTMODE == 0) {
        u16* o = out + (size_t)t * CH;
        o[tid] = f2b(y0); o[tid + 256] = f2b(y1);
    } else {
        bool mk = mask[t] != 0;
        int pr = (t >> 8) * LP + 4 + (t & 255);
        u16* o = out + (size_t)pr * CH;
        o[tid]       = mk ? f2b(y0) : (u16)0;
        o[tid + 256] = mk ? f2b(y1) : (u16)0;
    }
}

// ---------------------------------------------------------------- conv weight transpose
// src fp32 [P][9][Cin][Cout] -> dst bf16 [P][Cout][9*Cin]
__global__ __launch_bounds__(256) void tp_conv(const float* __restrict__ src,
    u16* __restrict__ dst)
{
    __shared__ float tile[32][33];
    int z = blockIdx.z, p = z / 9, t = z % 9;
    int ci0 = blockIdx.y * 32, co0 = blockIdx.x * 32;
    int tx = threadIdx.x, ty = threadIdx.y;   // 32 x 8
    #pragma unroll
    for (int yy = 0; yy < 4; yy++) {
        int i = ty + yy*8;
        tile[i][tx] = src[((size_t)z*512 + ci0 + i)*512 + co0 + tx];
    }
    __syncthreads();
    #pragma unroll
    for (int yy = 0; yy < 4; yy++) {
        int i = ty + yy*8;
        dst[((size_t)p*512 + co0 + i)*4608 + (size_t)t*512 + ci0 + tx] = f2b(tile[tx][i]);
    }
}

// ---------------------------------------------------------------- head transpose (fp32 [16][256][256])
__global__ __launch_bounds__(256) void tp_head(const float* __restrict__ src,
    float* __restrict__ dst)
{
    __shared__ float tile[32][33];
    int b = blockIdx.z;
    int i0 = blockIdx.y * 32, j0 = blockIdx.x * 32;
    int tx = threadIdx.x & 31, ty = threadIdx.x >> 5;   // 32 x 8
    #pragma unroll
    for (int yy = 0; yy < 4; yy++) {
        int i = ty + yy*8;
        tile[i][tx] = src[((size_t)b*256 + i0 + i)*256 + j0 + tx];
    }
    __syncthreads();
    #pragma unroll
    for (int yy = 0; yy < 4; yy++) {
        int i = ty + yy*8;
        dst[((size_t)b*256 + j0 + i)*256 + i0 + tx] = tile[tx][i];
    }
}

// ---------------------------------------------------------------- MFMA GEMM, m97 structure
// C[M,N] = act(alpha * A @ B^T + bias); A bf16 [M][K] (CONV: padded parser layout),
// B bf16 [Npad][K]. OUT: 0 fp32, 1 bf16, 2 fp32 +=, 3 fp32 atomicAdd (split-K).
// swz: 0 none; 1 XCD-chunked n-fast; 2 XCD-chunked m-fast (B-panel resident).
template<int BM, bool CONV, int ACT, int OUT, int SPLITK>
__global__ __launch_bounds__(256) void gemm2(
    const u16* __restrict__ A, const u16* __restrict__ B,
    const float* __restrict__ bias, void* __restrict__ Cv,
    int M, int N, int K, float alpha, long sA, long sB, long sC, int swz)
{
    constexpr int MI = BM / 32;
    __shared__ __align__(16) u16 As[32 * BM];  // [4 kq][BM][8]
    __shared__ __align__(16) u16 Bs[4096];     // [4 kq][128][8]

    int bx = blockIdx.x, by = blockIdx.y;
    if (swz) {
        int nwg = gridDim.x * gridDim.y;            // caller guarantees nwg % 8 == 0
        int bid = by * gridDim.x + bx;
        bid = (bid & 7) * (nwg >> 3) + (bid >> 3);
        if (swz == 2) { by = bid % gridDim.y; bx = bid / gridDim.y; }
        else          { bx = bid % gridDim.x; by = bid / gridDim.x; }
    }
    const int tid  = threadIdx.x;
    const int lane = tid & 63, wave = tid >> 6;
    const int q = lane >> 4, ln = lane & 15;
    const int wm = wave >> 1, wn = wave & 1;
    const int m0 = by * BM, n0 = bx * 128;
    const int z  = blockIdx.z;

    int kbeg = 0, kend = K;
    if (SPLITK > 1) {
        int ks = K / SPLITK;
        kbeg = z * ks; kend = kbeg + ks;
    } else {
        A += (size_t)z * sA; B += (size_t)z * sB;
    }

    f32x4 acc[MI][4];
    #pragma unroll
    for (int i = 0; i < MI; i++)
        #pragma unroll
        for (int j = 0; j < 4; j++)
            #pragma unroll
            for (int r = 0; r < 4; r++) acc[i][j][r] = 0.f;

    for (int k0 = kbeg; k0 < kend; k0 += 32) {
        // ---- stage A ----
        if (CONV) {
            // padded pre-masked layout: row (b*LP + l + tap), col (k0&511)+wave*8
            int tap = k0 >> 9;
            int ci  = (k0 & 511) + wave*8;
            int gr  = m0 + lane;
            int pr  = (gr >> 8) * LP + (gr & 255) + tap;
            gll16(A + (size_t)pr * CH + ci, As + wave*512);
        } else if (BM == 128) {
            #pragma unroll
            for (int t = 0; t < 2; t++) {
                int c = wave + t*4;                 // chunk 0..7: kq=c>>1, rows (c&1)*64+lane
                int kq = c >> 1, rh = (c & 1) << 6;
                gll16(A + (size_t)(m0 + rh + lane) * K + k0 + kq*8, As + c*512);
            }
        } else {
            gll16(A + (size_t)(m0 + lane) * K + k0 + wave*8, As + wave*512);
        }
        // ---- stage B ----
        #pragma unroll
        for (int t = 0; t < 2; t++) {
            int c = wave + t*4;
            int kq = c >> 1, rh = (c & 1) << 6;
            gll16(B + (size_t)(n0 + rh + lane) * K + k0 + kq*8, Bs + c*512);
        }
        __syncthreads();
        short8 af[MI], bf[4];
        #pragma unroll
        for (int f = 0; f < MI; f++)
            af[f] = *(const short8*)&As[q*(BM*8) + (wm*(BM/2) + f*16 + ln)*8];
        #pragma unroll
        for (int g = 0; g < 4; g++)
            bf[g] = *(const short8*)&Bs[q*1024 + (wn*64 + g*16 + ln)*8];
        #pragma unroll
        for (int f = 0; f < MI; f++)
            #pragma unroll
            for (int g = 0; g < 4; g++)
                acc[f][g] = __builtin_amdgcn_mfma_f32_16x16x32_bf16(af[f], bf[g], acc[f][g], 0, 0, 0);
        __syncthreads();
    }
    // ---- epilogue ----
    float* Cf = (float*)Cv; u16* Cb = (u16*)Cv;
    size_t zoff = (SPLITK > 1) ? 0 : (size_t)z * sC;
    bool addb = bias && (SPLITK == 1 || z == 0);
    #pragma unroll
    for (int f = 0; f < MI; f++) {
        int row0 = m0 + wm*(BM/2) + f*16 + q*4;
        #pragma unroll
        for (int g = 0; g < 4; g++) {
            int col = n0 + wn*64 + g*16 + ln;
            if (col < N) {
                #pragma unroll
                for (int r = 0; r < 4; r++) {
                    float v = acc[f][g][r] * alpha;
                    if (addb) v += bias[col];
                    if (ACT == 1) v = v > 0.f ? v : 0.01f * v;
                    size_t idx = zoff + (size_t)(row0 + r) * N + col;
                    if (OUT == 0)      Cf[idx] = v;
                    else if (OUT == 1) Cb[idx] = f2b(v);
                    else if (OUT == 2) Cf[idx] += v;
                    else               atomicAdd(&Cf[idx], v);
                }
            }
        }
    }
}

// ---------------------------------------------------------------- parser softmax
__global__ __launch_bounds__(256) void softmax_head(float* __restrict__ sc,
    const u8* __restrict__ mask)
{
    int bi = blockIdx.x;              // b*256 + i
    int b = bi >> 8, i = bi & 255;
    int j = threadIdx.x;
    float* rowp = sc + (size_t)bi * CL;
    bool valid = mask[(b << 8) | j] != 0;
    float v = valid ? rowp[j] : -1e30f;
    float mx = v;
    #pragma unroll
    for (int o = 32; o; o >>= 1) mx = fmaxf(mx, __shfl_down(mx, o));
    __shared__ float rm[4], rsum[4];
    int w = j >> 6, lane = j & 63;
    if (lane == 0) rm[w] = mx;
    __syncthreads();
    mx = fmaxf(fmaxf(rm[0], rm[1]), fmaxf(rm[2], rm[3]));
    float e = valid ? __expf(v - mx) : 0.f;
    float ssum = e;
    #pragma unroll
    for (int o = 32; o; o >>= 1) ssum += __shfl_down(ssum, o);
    if (lane == 0) rsum[w] = ssum;
    __syncthreads();
    ssum = rsum[0] + rsum[1] + rsum[2] + rsum[3];
    float r = e / fmaxf(ssum, 1e-30f);
    if (j == i) r = 0.f;
    rowp[j] = r;
}

// ---------------------------------------------------------------- attention
__global__ __launch_bounds__(256) void attn_k(const u16* __restrict__ qkv,
    const float* __restrict__ head, const float* __restrict__ headT,
    const float* __restrict__ relw, const u8* __restrict__ mask,
    u16* __restrict__ ctx, int layer)
{
    __shared__ __align__(16) u16 Ks[CL * CDH];
    __shared__ __align__(16) u16 Vs[CL * CDH];
    int bx = blockIdx.x;
    int b = bx >> 4, hd = (bx >> 1) & 7, qh = bx & 1;
    int tid = threadIdx.x;

    #pragma unroll
    for (int r = 0; r < 8; r++) {
        int ef = tid + 256 * r;
        int j = ef >> 3, d8 = (ef & 7) * 8;
        const u16* ps = qkv + (size_t)(b*256 + j) * 1536 + 512 + hd*64 + d8;
        *(uint4*)&Ks[j*64 + d8] = *(const uint4*)ps;
        *(uint4*)&Vs[j*64 + d8] = *(const uint4*)(ps + 512);
    }

    int qi = qh * 128 + (tid >> 1);
    int half = tid & 1;
    float qv[CDH];
    {
        const u16* qp = qkv + (size_t)(b*256 + qi) * 1536 + hd*64;
        #pragma unroll
        for (int c = 0; c < 8; c++) {
            uint4 u = *(const uint4*)(qp + c*8);
            unsigned uu[4] = {u.x, u.y, u.z, u.w};
            #pragma unroll
            for (int p2 = 0; p2 < 4; p2++) {
                qv[c*8 + p2*2]     = b2f((u16)(uu[p2] & 0xffffu));
                qv[c*8 + p2*2 + 1] = b2f((u16)(uu[p2] >> 16));
            }
        }
    }
    float r0 = relw[((layer << 3) + hd) * 2 + 0];
    float r1 = relw[((layer << 3) + hd) * 2 + 1];
    float e0 = __expf(r0), e1 = __expf(r1);
    float w0 = e0 / (e0 + e1), w1 = 1.f - w0;

    __syncthreads();

    const float* h1 = head  + ((size_t)b << 16) + ((size_t)qi << 8);  // head[b,qi,:]
    const float* h2 = headT + ((size_t)b << 16) + ((size_t)qi << 8);  // head[b,:,qi] coalesced
    const u8* mb = mask + (b << 8);

    float m = -1e30f, lsum = 0.f;
    float acc[CDH];
    #pragma unroll
    for (int d = 0; d < CDH; d++) acc[d] = 0.f;

    for (int jj = 0; jj < 128; jj++) {
        int j = half * 128 + jj;
        if (!mb[j]) continue;
        float dot = 0.f;
        #pragma unroll
        for (int d = 0; d < CDH; d++) dot += qv[d] * b2f(Ks[(j << 6) + d]);
        float s = dot * 0.125f + w0 * h1[j] + w1 * h2[j];
        float mn = fmaxf(m, s);
        float c = __expf(m - mn);
        float p = __expf(s - mn);
        lsum = lsum * c + p;
        #pragma unroll
        for (int d = 0; d < CDH; d++) acc[d] = acc[d] * c + p * b2f(Vs[(j << 6) + d]);
        m = mn;
    }
    {
        float mo = __shfl_xor(m, 1);
        float lo = __shfl_xor(lsum, 1);
        float M  = fmaxf(m, mo);
        float cs = __expf(m - M);
        float co = __expf(mo - M);
        lsum = lsum * cs + lo * co;
        #pragma unroll
        for (int d = 0; d < CDH; d++) {
            float ao = __shfl_xor(acc[d], 1);
            acc[d] = acc[d] * cs + ao * co;
        }
    }
    if (half == 0) {
        float inv = 1.f / fmaxf(lsum, 1e-30f);
        u16* cp = ctx + (size_t)(b*256 + qi) * CH + (hd << 6);
        #pragma unroll
        for (int d = 0; d < CDH; d++) cp[d] = f2b(acc[d] * inv);
    }
}

// ---------------------------------------------------------------- launch
extern "C" void kernel_launch(void* const* d_in, const int* in_sizes, int n_in,
                              void* d_out, int out_size, void* d_ws, size_t ws_size,
                              hipStream_t stream)
{
    const int*   x        = (const int*)d_in[0];
    const float* emb      = (const float*)d_in[2];
    const float* conv_w   = (const float*)d_in[3];
    const float* conv_b   = (const float*)d_in[4];
    const float* parent_w = (const float*)d_in[5];
    const float* parent_b = (const float*)d_in[6];
    const float* child_w  = (const float*)d_in[7];
    const float* child_b  = (const float*)d_in[8];
    const float* rel_w    = (const float*)d_in[9];
    const float* qkv_w    = (const float*)d_in[10];
    const float* qkv_b    = (const float*)d_in[11];
    const float* out_w    = (const float*)d_in[12];
    const float* out_b    = (const float*)d_in[13];
    const float* ln1_s    = (const float*)d_in[14];
    const float* ln1_b    = (const float*)d_in[15];
    const float* ln2_s    = (const float*)d_in[16];
    const float* ln2_b    = (const float*)d_in[17];
    const float* ff1_w    = (const float*)d_in[18];
    const float* ff1_b    = (const float*)d_in[19];
    const float* ff2_w    = (const float*)d_in[20];
    const float* ff2_b    = (const float*)d_in[21];
    const float* norm_s   = (const float*)d_in[22];
    const float* norm_b   = (const float*)d_in[23];
    const float* out_bias = (const float*)d_in[24];

    float* ws = (float*)d_ws;
    // ---- workspace layout (float offsets) ----
    float* h      = ws;                                  // fp32 residual (8 MB)
    float* headp  = ws + 2097152;                        // 4 MB fp32 (B,L,L)
    u16*   abuf   = (u16*)(ws + 3145728);                // 4 MB bf16 LN out
    u16*   Rb     = (u16*)(ws + 4194304);                // 12 MB region
    u16*   qkvb   = Rb;                                  //   qkv bf16 (12 MB)
    u16*   ppad   = Rb;                                  //   parser padded input (4.33 MB, dead before parentb)
    u16*   parentb= Rb;                                  //   parser alias (after convs)
    u16*   childb = Rb + 2097152;
    u16*   convo  = Rb + 4194304;                        //   conv out bf16 (4 MB)
    u16*   ctxb   = (u16*)(ws + 7340032);                // 4 MB bf16 ctx
    u16*   ff1b   = (u16*)(ws + 8388608);                // 16 MB bf16 ff1
    u16*   convwb = (u16*)(ws + 7340032);                // conv W bf16 (18.9 MB, alias ctx+ff1; dead before transformer)
    u8*    maskb  = (u8*)(ws + 12582912);                // 4 KB
    u16*   ebf16  = (u16*)(ws + 12583936);               // emb bf16 padded [10112][512] (10.35 MB)
    u16*   qkvwb  = (u16*)(ws + 15172608);               // 9.4 MB
    u16*   outwb  = (u16*)(ws + 17531904);               // 3.1 MB
    u16*   ff1wb  = (u16*)(ws + 18318336);               // 12.6 MB
    u16*   ff2wb  = (u16*)(ws + 21464064);               // 12.6 MB
    u16*   parwb  = (u16*)(ws + 24609792);               // 0.5 MB
    u16*   chlwb  = (u16*)(ws + 24740864);               // 0.5 MB  (total ~99.5 MB)
    float* headT  = (float*)d_out;                       // 4 MB scratch; overwritten by final GEMM

    // ---- one-time weight conversion to bf16 ----
    tp_conv<<<dim3(16,16,36), dim3(32,8), 0, stream>>>(conv_w, convwb);
    cvt_k<<<2528, 256, 0, stream>>>(emb,      ebf16, (long)CNTOK*CH, (long)NTOKP*CH);
    cvt_k<<<2304, 256, 0, stream>>>(qkv_w,    qkvwb, 4718592L, 4718592L);
    cvt_k<<< 768, 256, 0, stream>>>(out_w,    outwb, 1572864L, 1572864L);
    cvt_k<<<3072, 256, 0, stream>>>(ff1_w,    ff1wb, 6291456L, 6291456L);
    cvt_k<<<3072, 256, 0, stream>>>(ff2_w,    ff2wb, 6291456L, 6291456L);
    cvt_k<<< 128, 256, 0, stream>>>(parent_w, parwb,  262144L,  262144L);
    cvt_k<<< 128, 256, 0, stream>>>(child_w,  chlwb,  262144L,  262144L);

    // ---- parser (padded pre-masked conv input) ----
    hipMemsetAsync(ppad, 0, (size_t)CB * LP * CH * 2, stream);   // zero halos (+everything once)
    embed2_k<<<CT, 256, 0, stream>>>(x, emb, h, ppad, maskb);
    for (int p = 0; p < CP; p++) {
        gemm2<64,true,0,1,1><<<dim3(4,64,1), 256, 0, stream>>>(
            ppad, convwb + (size_t)p*512*4608, conv_b + p*512, convo,
            CT, 512, 4608, 1.f, 0, 0, 0, 2);
        if (p < CP-1)
            ln_k<true,false,true,1><<<CT, 256, 0, stream>>>(convo, nullptr, nullptr, ppad, maskb);
        else
            ln_k<true,false,true,0><<<CT, 256, 0, stream>>>(convo, nullptr, nullptr, abuf, nullptr);
    }
    gemm2<64,false,0,1,1><<<dim3(4,64,1), 256, 0, stream>>>(
        abuf, parwb, parent_b, parentb, CT, 512, 512, 1.f, 0, 0, 0, 2);
    gemm2<64,false,0,1,1><<<dim3(4,64,1), 256, 0, stream>>>(
        abuf, chlwb, child_b, childb, CT, 512, 512, 1.f, 0, 0, 0, 2);
    gemm2<64,false,0,0,1><<<dim3(2,4,16), 256, 0, stream>>>(
        childb, parentb, nullptr, headp, 256, 256, 512, 1.f/512.f,
        131072, 131072, 65536, 0);
    softmax_head<<<CT, 256, 0, stream>>>(headp, maskb);
    tp_head<<<dim3(8,8,16), 256, 0, stream>>>(headp, headT);

    // ---- transformer ----
    for (int l = 0; l < CNL; l++) {
        ln_k<false,true,false,0><<<CT, 256, 0, stream>>>(h, ln1_s + l*CH, ln1_b + l*CH, abuf, nullptr);
        gemm2<128,false,0,1,1><<<dim3(12,32,1), 256, 0, stream>>>(
            abuf, qkvwb + (size_t)l*1536*512, qkv_b + l*1536, qkvb,
            CT, 1536, 512, 1.f, 0, 0, 0, 1);
        attn_k<<<256, 256, 0, stream>>>(qkvb, headp, headT, rel_w, maskb, ctxb, l);
        gemm2<64,false,0,3,2><<<dim3(4,64,2), 256, 0, stream>>>(
            ctxb, outwb + (size_t)l*512*512, out_b + l*512, h,
            CT, 512, 512, 1.f, 0, 0, 0, 2);
        ln_k<false,true,false,0><<<CT, 256, 0, stream>>>(h, ln2_s + l*CH, ln2_b + l*CH, abuf, nullptr);
        gemm2<128,false,1,1,1><<<dim3(16,32,1), 256, 0, stream>>>(
            abuf, ff1wb + (size_t)l*2048*512, ff1_b + l*2048, ff1b,
            CT, 2048, 512, 1.f, 0, 0, 0, 1);
        gemm2<64,false,0,3,2><<<dim3(4,64,2), 256, 0, stream>>>(
            ff1b, ff2wb + (size_t)l*512*2048, ff2_b + l*512, h,
            CT, 512, 2048, 1.f, 0, 0, 0, 2);
    }
    ln_k<false,true,false,0><<<CT, 256, 0, stream>>>(h, norm_s, norm_b, abuf, nullptr);
    // logits: 79x32 grid, m-fast XCD chunks (B panel L2-resident)
    gemm2<128,false,0,0,1><<<dim3(79,32,1), 256, 0, stream>>>(
        abuf, ebf16, out_bias, d_out, CT, CNTOK, 512, 1.f, 0, 0, 0, 2);
}

// Round 3
// 2379.478 us; speedup vs baseline: 1.2188x; 1.0554x over previous
//
#include <hip/hip_runtime.h>
#include <hip/hip_bf16.h>

// StructFormer forward, MI355X. Round 5:
// - gemm2: 2-phase double-buffered K-loop (stage next tile before computing current,
//   ONE barrier per K-step) -> load latency hidden under MFMA+ds_read
// - conv: split-K=2 + fp32 atomicAdd into convo (residual-h region, dead during parser);
//   embed split into embed_p (parser) / embed_h (transformer)
// - qkv/ff1 -> BM=64 grids (768/1024 blocks = 3-4/CU) for latency hiding via TLP
// B=16 L=256 H=512 NH=8 DH=64 NL=6 NTOK=10000 P=4 K=9 DFF=2048

typedef unsigned short u16;
typedef unsigned char  u8;
typedef short short8 __attribute__((ext_vector_type(8)));
typedef float f32x4  __attribute__((ext_vector_type(4)));

static constexpr int CB=16, CL=256, CH=512, CNH=8, CDH=64, CNL=6;
static constexpr int CNTOK=10000, CP=4, CKS=9, CDFF=2048, CT=CB*CL;
static constexpr int NTOKP=10112;   // 10000 padded to multiple of 128
static constexpr int LP=264;        // padded parser row stride (4 halo + 256 + 4 halo)

__device__ __forceinline__ u16 f2b(float x){
    union { float f; unsigned u; } v; v.f = x;
    unsigned r = v.u + 0x7fffu + ((v.u >> 16) & 1u);   // round-to-nearest-even
    return (u16)(r >> 16);
}
__device__ __forceinline__ float b2f(u16 u){
    union { unsigned u; float f; } v; v.u = ((unsigned)u) << 16; return v.f;
}
__device__ __forceinline__ unsigned pack2(float a, float b){
    return (unsigned)f2b(a) | ((unsigned)f2b(b) << 16);
}
__device__ __forceinline__ void gll16(const void* g, void* l){
    __builtin_amdgcn_global_load_lds(
        (__attribute__((address_space(1))) void*)g,
        (__attribute__((address_space(3))) void*)l, 16, 0, 0);
}

// ---------------------------------------------------------------- fp32 -> bf16 convert (pad tail with zeros)
__global__ __launch_bounds__(256) void cvt_k(const float* __restrict__ in,
    u16* __restrict__ out, long n, long total)
{
    long i = ((long)blockIdx.x * 256 + threadIdx.x) * 8;
    if (i >= total) return;
    uint4 o;
    if (i < n) {
        float4 a = *(const float4*)(in + i);
        float4 b = *(const float4*)(in + i + 4);
        o.x = pack2(a.x, a.y); o.y = pack2(a.z, a.w);
        o.z = pack2(b.x, b.y); o.w = pack2(b.z, b.w);
    } else { o.x = o.y = o.z = o.w = 0u; }
    *(uint4*)(out + i) = o;
}

// ---------------------------------------------------------------- embed: parser input (padded, masked) + mask
__global__ __launch_bounds__(256) void embed_p(const int* __restrict__ x,
    const float* __restrict__ emb, u16* __restrict__ ppad, u8* __restrict__ maskb)
{
    int t = blockIdx.x, tid = threadIdx.x;
    int tok = x[t];
    bool mk = (tok != 0);
    if (tid == 0) maskb[t] = mk ? 1 : 0;
    const float* e = emb + (size_t)tok * CH;
    int pr = (t >> 8) * LP + 4 + (t & 255);
    u16* ap = ppad + (size_t)pr * CH;
    ap[tid]       = mk ? f2b(e[tid])       : (u16)0;
    ap[tid + 256] = mk ? f2b(e[tid + 256]) : (u16)0;
}

// ---------------------------------------------------------------- embed: fp32 residual (after parser)
__global__ __launch_bounds__(256) void embed_h(const int* __restrict__ x,
    const float* __restrict__ emb, float* __restrict__ h)
{
    int t = blockIdx.x, tid = threadIdx.x;
    const float* e = emb + (size_t)x[t] * CH;
    float* hp = h + (size_t)t * CH;
    hp[tid] = e[tid]; hp[tid + 256] = e[tid + 256];
}

// ---------------------------------------------------------------- layernorm
// OUTMODE 0: plain [4096][512] bf16; 1: padded parser layout + mask-zeroing
template<bool INBF, bool AFFINE, bool DOTANH, int OUTMODE>
__global__ __launch_bounds__(256) void ln_k(const void* __restrict__ in,
    const float* __restrict__ s, const float* __restrict__ b, u16* __restrict__ out,
    const u8* __restrict__ mask)
{
    int t = blockIdx.x, tid = threadIdx.x;
    float x0, x1;
    if (INBF) {
        const u16* row = (const u16*)in + (size_t)t * CH;
        x0 = b2f(row[tid]); x1 = b2f(row[tid + 256]);
    } else {
        const float* row = (const float*)in + (size_t)t * CH;
        x0 = row[tid]; x1 = row[tid + 256];
    }
    float sum = x0 + x1, sq = x0*x0 + x1*x1;
    #pragma unroll
    for (int o = 32; o; o >>= 1) { sum += __shfl_down(sum, o); sq += __shfl_down(sq, o); }
    __shared__ float rs[4], rq[4];
    int w = tid >> 6, lane = tid & 63;
    if (lane == 0) { rs[w] = sum; rq[w] = sq; }
    __syncthreads();
    sum = rs[0] + rs[1] + rs[2] + rs[3];
    sq  = rq[0] + rq[1] + rq[2] + rq[3];
    float mean = sum * (1.f/512.f);
    float var  = fmaxf(sq * (1.f/512.f) - mean*mean, 0.f);
    float rstd = rsqrtf(var + 1e-5f);
    float y0 = (x0 - mean) * rstd, y1 = (x1 - mean) * rstd;
    if (AFFINE) {
        y0 = y0 * s[tid]       + b[tid];
        y1 = y1 * s[tid + 256] + b[tid + 256];
    }
    if (DOTANH) { y0 = tanhf(y0); y1 = tanhf(y1); }
    if (OUTMODE == 0) {
        u16* o = out + (size_t)t * CH;
        o[tid] = f2b(y0); o[tid + 256] = f2b(y1);
    } else {
        bool mk = mask[t] != 0;
        int pr = (t >> 8) * LP + 4 + (t & 255);
        u16* o = out + (size_t)pr * CH;
        o[tid]       = mk ? f2b(y0) : (u16)0;
        o[tid + 256] = mk ? f2b(y1) : (u16)0;
    }
}

// ---------------------------------------------------------------- conv weight transpose
// src fp32 [P][9][Cin][Cout] -> dst bf16 [P][Cout][9*Cin]
__global__ __launch_bounds__(256) void tp_conv(const float* __restrict__ src,
    u16* __restrict__ dst)
{
    __shared__ float tile[32][33];
    int z = blockIdx.z, p = z / 9, t = z % 9;
    int ci0 = blockIdx.y * 32, co0 = blockIdx.x * 32;
    int tx = threadIdx.x, ty = threadIdx.y;   // 32 x 8
    #pragma unroll
    for (int yy = 0; yy < 4; yy++) {
        int i = ty + yy*8;
        tile[i][tx] = src[((size_t)z*512 + ci0 + i)*512 + co0 + tx];
    }
    __syncthreads();
    #pragma unroll
    for (int yy = 0; yy < 4; yy++) {
        int i = ty + yy*8;
        dst[((size_t)p*512 + co0 + i)*4608 + (size_t)t*512 + ci0 + tx] = f2b(tile[tx][i]);
    }
}

// ---------------------------------------------------------------- head transpose (fp32 [16][256][256])
__global__ __launch_bounds__(256) void tp_head(const float* __restrict__ src,
    float* __restrict__ dst)
{
    __shared__ float tile[32][33];
    int b = blockIdx.z;
    int i0 = blockIdx.y * 32, j0 = blockIdx.x * 32;
    int tx = threadIdx.x & 31, ty = threadIdx.x >> 5;   // 32 x 8
    #pragma unroll
    for (int yy = 0; yy < 4; yy++) {
        int i = ty + yy*8;
        tile[i][tx] = src[((size_t)b*256 + i0 + i)*256 + j0 + tx];
    }
    __syncthreads();
    #pragma unroll
    for (int yy = 0; yy < 4; yy++) {
        int i = ty + yy*8;
        dst[((size_t)b*256 + j0 + i)*256 + i0 + tx] = tile[tx][i];
    }
}

// ---------------------------------------------------------------- MFMA GEMM, 2-phase double-buffered
// C[M,N] = act(alpha * A @ B^T + bias); A bf16 [M][K] (CONV: padded parser layout),
// B bf16 [Npad][K]. OUT: 0 fp32, 1 bf16, 2 fp32 +=, 3 fp32 atomicAdd (split-K).
// swz: 0 none; 1 XCD-chunked n-fast; 2 XCD-chunked m-fast (B-panel resident).
// K-loop: stage(next buf) -> ds_read+MFMA(cur buf) -> ONE __syncthreads -> swap.
template<int BM, bool CONV, int ACT, int OUT, int SPLITK>
__global__ __launch_bounds__(256) void gemm2(
    const u16* __restrict__ A, const u16* __restrict__ B,
    const float* __restrict__ bias, void* __restrict__ Cv,
    int M, int N, int K, float alpha, long sA, long sB, long sC, int swz)
{
    constexpr int MI = BM / 32;
    __shared__ __align__(16) u16 As[2 * 32 * BM];  // 2 x [4 kq][BM][8]
    __shared__ __align__(16) u16 Bs[2 * 4096];     // 2 x [4 kq][128][8]

    int bx = blockIdx.x, by = blockIdx.y;
    if (swz) {
        int nwg = gridDim.x * gridDim.y;            // caller guarantees nwg % 8 == 0
        int bid = by * gridDim.x + bx;
        bid = (bid & 7) * (nwg >> 3) + (bid >> 3);
        if (swz == 2) { by = bid % gridDim.y; bx = bid / gridDim.y; }
        else          { bx = bid % gridDim.x; by = bid / gridDim.x; }
    }
    const int tid  = threadIdx.x;
    const int lane = tid & 63, wave = tid >> 6;
    const int q = lane >> 4, ln = lane & 15;
    const int wm = wave >> 1, wn = wave & 1;
    const int m0 = by * BM, n0 = bx * 128;
    const int z  = blockIdx.z;

    int kbeg = 0, kend = K;
    if (SPLITK > 1) {
        int ks = K / SPLITK;
        kbeg = z * ks; kend = kbeg + ks;
    } else {
        A += (size_t)z * sA; B += (size_t)z * sB;
    }

    f32x4 acc[MI][4];
    #pragma unroll
    for (int i = 0; i < MI; i++)
        #pragma unroll
        for (int j = 0; j < 4; j++)
            #pragma unroll
            for (int r = 0; r < 4; r++) acc[i][j][r] = 0.f;

    auto stage = [&](int buf, int k0) {
        u16* Ad = As + buf * (32 * BM);
        u16* Bd = Bs + buf * 4096;
        if (CONV) {
            // padded pre-masked layout: row (b*LP + l + tap), col (k0&511)+wave*8
            int tap = k0 >> 9;
            int ci  = (k0 & 511) + wave*8;
            int gr  = m0 + lane;
            int pr  = (gr >> 8) * LP + (gr & 255) + tap;
            gll16(A + (size_t)pr * CH + ci, Ad + wave*512);
        } else if (BM == 128) {
            #pragma unroll
            for (int t = 0; t < 2; t++) {
                int c = wave + t*4, kq = c >> 1, rh = (c & 1) << 6;
                gll16(A + (size_t)(m0 + rh + lane) * K + k0 + kq*8, Ad + c*512);
            }
        } else {
            gll16(A + (size_t)(m0 + lane) * K + k0 + wave*8, Ad + wave*512);
        }
        #pragma unroll
        for (int t = 0; t < 2; t++) {
            int c = wave + t*4, kq = c >> 1, rh = (c & 1) << 6;
            gll16(B + (size_t)(n0 + rh + lane) * K + k0 + kq*8, Bd + c*512);
        }
    };

    stage(0, kbeg);
    __syncthreads();                       // buf0 ready
    int cur = 0;
    for (int k0 = kbeg; k0 < kend; k0 += 32) {
        if (k0 + 32 < kend) stage(cur ^ 1, k0 + 32);   // issue next-tile loads first
        const u16* Ac = As + cur * (32 * BM);
        const u16* Bc = Bs + cur * 4096;
        short8 af[MI], bg[4];
        #pragma unroll
        for (int f = 0; f < MI; f++)
            af[f] = *(const short8*)&Ac[q*(BM*8) + (wm*(BM/2) + f*16 + ln)*8];
        #pragma unroll
        for (int g = 0; g < 4; g++)
            bg[g] = *(const short8*)&Bc[q*1024 + (wn*64 + g*16 + ln)*8];
        #pragma unroll
        for (int f = 0; f < MI; f++)
            #pragma unroll
            for (int g = 0; g < 4; g++)
                acc[f][g] = __builtin_amdgcn_mfma_f32_16x16x32_bf16(af[f], bg[g], acc[f][g], 0, 0, 0);
        __syncthreads();                   // drain next loads + fence reads before overwrite
        cur ^= 1;
    }
    // ---- epilogue ----
    float* Cf = (float*)Cv; u16* Cb = (u16*)Cv;
    size_t zoff = (SPLITK > 1) ? 0 : (size_t)z * sC;
    bool addb = bias && (SPLITK == 1 || z == 0);
    #pragma unroll
    for (int f = 0; f < MI; f++) {
        int row0 = m0 + wm*(BM/2) + f*16 + q*4;
        #pragma unroll
        for (int g = 0; g < 4; g++) {
            int col = n0 + wn*64 + g*16 + ln;
            if (col < N) {
                #pragma unroll
                for (int r = 0; r < 4; r++) {
                    float v = acc[f][g][r] * alpha;
                    if (addb) v += bias[col];
                    if (ACT == 1) v = v > 0.f ? v : 0.01f * v;
                    size_t idx = zoff + (size_t)(row0 + r) * N + col;
                    if (OUT == 0)      Cf[idx] = v;
                    else if (OUT == 1) Cb[idx] = f2b(v);
                    else if (OUT == 2) Cf[idx] += v;
                    else               atomicAdd(&Cf[idx], v);
                }
            }
        }
    }
}

// ---------------------------------------------------------------- parser softmax
__global__ __launch_bounds__(256) void softmax_head(float* __restrict__ sc,
    const u8* __restrict__ mask)
{
    int bi = blockIdx.x;              // b*256 + i
    int b = bi >> 8, i = bi & 255;
    int j = threadIdx.x;
    float* rowp = sc + (size_t)bi * CL;
    bool valid = mask[(b << 8) | j] != 0;
    float v = valid ? rowp[j] : -1e30f;
    float mx = v;
    #pragma unroll
    for (int o = 32; o; o >>= 1) mx = fmaxf(mx, __shfl_down(mx, o));
    __shared__ float rm[4], rsum[4];
    int w = j >> 6, lane = j & 63;
    if (lane == 0) rm[w] = mx;
    __syncthreads();
    mx = fmaxf(fmaxf(rm[0], rm[1]), fmaxf(rm[2], rm[3]));
    float e = valid ? __expf(v - mx) : 0.f;
    float ssum = e;
    #pragma unroll
    for (int o = 32; o; o >>= 1) ssum += __shfl_down(ssum, o);
    if (lane == 0) rsum[w] = ssum;
    __syncthreads();
    ssum = rsum[0] + rsum[1] + rsum[2] + rsum[3];
    float r = e / fmaxf(ssum, 1e-30f);
    if (j == i) r = 0.f;
    rowp[j] = r;
}

// ---------------------------------------------------------------- attention
__global__ __launch_bounds__(256) void attn_k(const u16* __restrict__ qkv,
    const float* __restrict__ head, const float* __restrict__ headT,
    const float* __restrict__ relw, const u8* __restrict__ mask,
    u16* __restrict__ ctx, int layer)
{
    __shared__ __align__(16) u16 Ks[CL * CDH];
    __shared__ __align__(16) u16 Vs[CL * CDH];
    int bx = blockIdx.x;
    int b = bx >> 4, hd = (bx >> 1) & 7, qh = bx & 1;
    int tid = threadIdx.x;

    #pragma unroll
    for (int r = 0; r < 8; r++) {
        int ef = tid + 256 * r;
        int j = ef >> 3, d8 = (ef & 7) * 8;
        const u16* ps = qkv + (size_t)(b*256 + j) * 1536 + 512 + hd*64 + d8;
        *(uint4*)&Ks[j*64 + d8] = *(const uint4*)ps;
        *(uint4*)&Vs[j*64 + d8] = *(const uint4*)(ps + 512);
    }

    int qi = qh * 128 + (tid >> 1);
    int half = tid & 1;
    float qv[CDH];
    {
        const u16* qp = qkv + (size_t)(b*256 + qi) * 1536 + hd*64;
        #pragma unroll
        for (int c = 0; c < 8; c++) {
            uint4 u = *(const uint4*)(qp + c*8);
            unsigned uu[4] = {u.x, u.y, u.z, u.w};
            #pragma unroll
            for (int p2 = 0; p2 < 4; p2++) {
                qv[c*8 + p2*2]     = b2f((u16)(uu[p2] & 0xffffu));
                qv[c*8 + p2*2 + 1] = b2f((u16)(uu[p2] >> 16));
            }
        }
    }
    float r0 = relw[((layer << 3) + hd) * 2 + 0];
    float r1 = relw[((layer << 3) + hd) * 2 + 1];
    float e0 = __expf(r0), e1 = __expf(r1);
    float w0 = e0 / (e0 + e1), w1 = 1.f - w0;

    __syncthreads();

    const float* h1 = head  + ((size_t)b << 16) + ((size_t)qi << 8);  // head[b,qi,:]
    const float* h2 = headT + ((size_t)b << 16) + ((size_t)qi << 8);  // head[b,:,qi] coalesced
    const u8* mb = mask + (b << 8);

    float m = -1e30f, lsum = 0.f;
    float acc[CDH];
    #pragma unroll
    for (int d = 0; d < CDH; d++) acc[d] = 0.f;

    for (int jj = 0; jj < 128; jj++) {
        int j = half * 128 + jj;
        if (!mb[j]) continue;
        float dot = 0.f;
        #pragma unroll
        for (int d = 0; d < CDH; d++) dot += qv[d] * b2f(Ks[(j << 6) + d]);
        float s = dot * 0.125f + w0 * h1[j] + w1 * h2[j];
        float mn = fmaxf(m, s);
        float c = __expf(m - mn);
        float p = __expf(s - mn);
        lsum = lsum * c + p;
        #pragma unroll
        for (int d = 0; d < CDH; d++) acc[d] = acc[d] * c + p * b2f(Vs[(j << 6) + d]);
        m = mn;
    }
    {
        float mo = __shfl_xor(m, 1);
        float lo = __shfl_xor(lsum, 1);
        float M  = fmaxf(m, mo);
        float cs = __expf(m - M);
        float co = __expf(mo - M);
        lsum = lsum * cs + lo * co;
        #pragma unroll
        for (int d = 0; d < CDH; d++) {
            float ao = __shfl_xor(acc[d], 1);
            acc[d] = acc[d] * cs + ao * co;
        }
    }
    if (half == 0) {
        float inv = 1.f / fmaxf(lsum, 1e-30f);
        u16* cp = ctx + (size_t)(b*256 + qi) * CH + (hd << 6);
        #pragma unroll
        for (int d = 0; d < CDH; d++) cp[d] = f2b(acc[d] * inv);
    }
}

// ---------------------------------------------------------------- launch
extern "C" void kernel_launch(void* const* d_in, const int* in_sizes, int n_in,
                              void* d_out, int out_size, void* d_ws, size_t ws_size,
                              hipStream_t stream)
{
    const int*   x        = (const int*)d_in[0];
    const float* emb      = (const float*)d_in[2];
    const float* conv_w   = (const float*)d_in[3];
    const float* conv_b   = (const float*)d_in[4];
    const float* parent_w = (const float*)d_in[5];
    const float* parent_b = (const float*)d_in[6];
    const float* child_w  = (const float*)d_in[7];
    const float* child_b  = (const float*)d_in[8];
    const float* rel_w    = (const float*)d_in[9];
    const float* qkv_w    = (const float*)d_in[10];
    const float* qkv_b    = (const float*)d_in[11];
    const float* out_w    = (const float*)d_in[12];
    const float* out_b    = (const float*)d_in[13];
    const float* ln1_s    = (const float*)d_in[14];
    const float* ln1_b    = (const float*)d_in[15];
    const float* ln2_s    = (const float*)d_in[16];
    const float* ln2_b    = (const float*)d_in[17];
    const float* ff1_w    = (const float*)d_in[18];
    const float* ff1_b    = (const float*)d_in[19];
    const float* ff2_w    = (const float*)d_in[20];
    const float* ff2_b    = (const float*)d_in[21];
    const float* norm_s   = (const float*)d_in[22];
    const float* norm_b   = (const float*)d_in[23];
    const float* out_bias = (const float*)d_in[24];

    float* ws = (float*)d_ws;
    // ---- workspace layout (float offsets) ----
    float* h      = ws;                                  // fp32 residual (8 MB)
    float* convo  = ws;                                  // parser-phase alias: fp32 conv out (8 MB)
    float* headp  = ws + 2097152;                        // 4 MB fp32 (B,L,L)
    u16*   abuf   = (u16*)(ws + 3145728);                // 4 MB bf16 LN out
    u16*   Rb     = (u16*)(ws + 4194304);                // 12 MB region
    u16*   qkvb   = Rb;                                  //   qkv bf16 (12 MB)
    u16*   ppad   = Rb;                                  //   parser padded input (4.33 MB, dead before parentb)
    u16*   parentb= Rb;                                  //   parser alias (after convs)
    u16*   childb = Rb + 2097152;
    u16*   ctxb   = (u16*)(ws + 7340032);                // 4 MB bf16 ctx
    u16*   ff1b   = (u16*)(ws + 8388608);                // 16 MB bf16 ff1
    u16*   convwb = (u16*)(ws + 7340032);                // conv W bf16 (18.9 MB, alias ctx+ff1; dead before transformer)
    u8*    maskb  = (u8*)(ws + 12582912);                // 4 KB
    u16*   ebf16  = (u16*)(ws + 12583936);               // emb bf16 padded [10112][512] (10.35 MB)
    u16*   qkvwb  = (u16*)(ws + 15172608);               // 9.4 MB
    u16*   outwb  = (u16*)(ws + 17531904);               // 3.1 MB
    u16*   ff1wb  = (u16*)(ws + 18318336);               // 12.6 MB
    u16*   ff2wb  = (u16*)(ws + 21464064);               // 12.6 MB
    u16*   parwb  = (u16*)(ws + 24609792);               // 0.5 MB
    u16*   chlwb  = (u16*)(ws + 24740864);               // 0.5 MB  (total ~99.5 MB)
    float* headT  = (float*)d_out;                       // 4 MB scratch; overwritten by final GEMM

    // ---- one-time weight conversion to bf16 ----
    tp_conv<<<dim3(16,16,36), dim3(32,8), 0, stream>>>(conv_w, convwb);
    cvt_k<<<2528, 256, 0, stream>>>(emb,      ebf16, (long)CNTOK*CH, (long)NTOKP*CH);
    cvt_k<<<2304, 256, 0, stream>>>(qkv_w,    qkvwb, 4718592L, 4718592L);
    cvt_k<<< 768, 256, 0, stream>>>(out_w,    outwb, 1572864L, 1572864L);
    cvt_k<<<3072, 256, 0, stream>>>(ff1_w,    ff1wb, 6291456L, 6291456L);
    cvt_k<<<3072, 256, 0, stream>>>(ff2_w,    ff2wb, 6291456L, 6291456L);
    cvt_k<<< 128, 256, 0, stream>>>(parent_w, parwb,  262144L,  262144L);
    cvt_k<<< 128, 256, 0, stream>>>(child_w,  chlwb,  262144L,  262144L);

    // ---- parser (padded pre-masked conv input; convo fp32 in h-region) ----
    hipMemsetAsync(ppad, 0, (size_t)CB * LP * CH * 2, stream);   // zero halos
    embed_p<<<CT, 256, 0, stream>>>(x, emb, ppad, maskb);
    for (int p = 0; p < CP; p++) {
        hipMemsetAsync(convo, 0, (size_t)CT * CH * 4, stream);
        gemm2<64,true,0,3,2><<<dim3(4,64,2), 256, 0, stream>>>(
            ppad, convwb + (size_t)p*512*4608, conv_b + p*512, convo,
            CT, 512, 4608, 1.f, 0, 0, 0, 2);
        if (p < CP-1)
            ln_k<false,false,true,1><<<CT, 256, 0, stream>>>(convo, nullptr, nullptr, ppad, maskb);
        else
            ln_k<false,false,true,0><<<CT, 256, 0, stream>>>(convo, nullptr, nullptr, abuf, nullptr);
    }
    gemm2<64,false,0,1,1><<<dim3(4,64,1), 256, 0, stream>>>(
        abuf, parwb, parent_b, parentb, CT, 512, 512, 1.f, 0, 0, 0, 2);
    gemm2<64,false,0,1,1><<<dim3(4,64,1), 256, 0, stream>>>(
        abuf, chlwb, child_b, childb, CT, 512, 512, 1.f, 0, 0, 0, 2);
    gemm2<64,false,0,0,1><<<dim3(2,4,16), 256, 0, stream>>>(
        childb, parentb, nullptr, headp, 256, 256, 512, 1.f/512.f,
        131072, 131072, 65536, 0);
    softmax_head<<<CT, 256, 0, stream>>>(headp, maskb);
    tp_head<<<dim3(8,8,16), 256, 0, stream>>>(headp, headT);
    embed_h<<<CT, 256, 0, stream>>>(x, emb, h);          // refill residual (convo now dead)

    // ---- transformer ----
    for (int l = 0; l < CNL; l++) {
        ln_k<false,true,false,0><<<CT, 256, 0, stream>>>(h, ln1_s + l*CH, ln1_b + l*CH, abuf, nullptr);
        gemm2<64,false,0,1,1><<<dim3(12,64,1), 256, 0, stream>>>(
            abuf, qkvwb + (size_t)l*1536*512, qkv_b + l*1536, qkvb,
            CT, 1536, 512, 1.f, 0, 0, 0, 1);
        attn_k<<<256, 256, 0, stream>>>(qkvb, headp, headT, rel_w, maskb, ctxb, l);
        gemm2<64,false,0,3,2><<<dim3(4,64,2), 256, 0, stream>>>(
            ctxb, outwb + (size_t)l*512*512, out_b + l*512, h,
            CT, 512, 512, 1.f, 0, 0, 0, 2);
        ln_k<false,true,false,0><<<CT, 256, 0, stream>>>(h, ln2_s + l*CH, ln2_b + l*CH, abuf, nullptr);
        gemm2<64,false,1,1,1><<<dim3(16,64,1), 256, 0, stream>>>(
            abuf, ff1wb + (size_t)l*2048*512, ff1_b + l*2048, ff1b,
            CT, 2048, 512, 1.f, 0, 0, 0, 1);
        gemm2<64,false,0,3,2><<<dim3(4,64,2), 256, 0, stream>>>(
            ff1b, ff2wb + (size_t)l*512*2048, ff2_b + l*512, h,
            CT, 512, 2048, 1.f, 0, 0, 0, 2);
    }
    ln_k<false,true,false,0><<<CT, 256, 0, stream>>>(h, norm_s, norm_b, abuf, nullptr);
    // logits: 79x32 grid, m-fast XCD chunks (B panel L2-resident)
    gemm2<128,false,0,0,1><<<dim3(79,32,1), 256, 0, stream>>>(
        abuf, ebf16, out_bias, d_out, CT, CNTOK, 512, 1.f, 0, 0, 0, 2);
}